// Round 7
// baseline (4211.667 us; speedup 1.0000x reference)
//
#include <hip/hip_runtime.h>
#include <cmath>

// Leaky RNN:  h_t = 0.9 h_{t-1} + 0.1 tanh(h W_hh + u_t W_uh + b_h);  y_t = h_t W_hy + b_y
// B=64, T=2048, N_in=128, N_h=512, N_out=128.
//
// Phase 2 (critical path): one WG per batch row, 512 threads = 8 waves, fits the 128-VGPR
// pin.  W_hh: 2 of 8 cols/lane LDS-resident (128 KiB, step-invariant) + 6 cols streamed
// from L2 (384 KB/step/CU) through a 2-group double buffer of 12 named uint4.
// MACs via v_pk_fma_f16 (full-rate packed f16; v_dot2_f32_f16 measured half-rate here):
// per column TWO half2 accumulators (even/odd pairs, 16-term f16 chains), combined to
// f32 before the LDS partial write.  Partials in part2[8][8][72] (conflict-free).
// h broadcast via LDS f16 pairs; U prefetched one step ahead; 2 barriers/step.
//
// ws: U (f16 [B*T][512], 128 MiB) | H (f16 [B*T][512], 128 MiB).
// Wpk (512 KiB packed f16 W_hh) lives in d_out (dead until y_gemm runs last).

#define NB 64
#define NT 2048
#define NI 128
#define NH 512
#define NO 128

typedef unsigned short u16;
typedef unsigned int u32;
typedef _Float16 half2_t __attribute__((ext_vector_type(2)));

__device__ __forceinline__ half2_t fmah2(half2_t a, half2_t b, half2_t c) {
#if __has_builtin(__builtin_elementwise_fma)
    return __builtin_elementwise_fma(a, b, c);   // v_pk_fma_f16
#else
    return a * b + c;
#endif
}
#define BCH(u) __builtin_bit_cast(half2_t, (u))

__device__ __forceinline__ u16 ftoh(float x) { return __builtin_bit_cast(u16, (_Float16)x); }
__device__ __forceinline__ float htof(u16 x) { return (float)__builtin_bit_cast(_Float16, x); }

__device__ __forceinline__ float hsum4(half2_t e, half2_t o) {
    return ((float)e[0] + (float)e[1]) + ((float)o[0] + (float)o[1]);
}

__device__ __forceinline__ u32 ldpair(const float* __restrict__ W, int k, int c) {
    half2_t v;
    v[0] = (_Float16)W[(size_t)k * NH + c];
    v[1] = (_Float16)W[(size_t)(k + 1) * NH + c];
    return __builtin_bit_cast(u32, v);
}

// ---------------- Phase 0: pack W_hh to f16 in consumer order ----------------
// Section A (LDS-resident, idx<8192):  w=idx>>10, r=idx&1023, t2=r>>6, q=t2>>1, i=t2&1,
//   l=r&63, col=8l+i.
// Section B (streamed, idx>=8192): j=idx-8192, w=j/3072, r=j%3072, t2=r>>6, q=t2/6,
//   i=t2%6, l=r&63, col=8l+2+i.
// Quad = k-pairs {kb,kb+2,kb+4,kb+6}, kb=64w+8q.
__global__ __launch_bounds__(256) void wpack(const float* __restrict__ Whh,
                                             uint4* __restrict__ Wpk) {
    const int idx = blockIdx.x * 256 + threadIdx.x;   // 0..32767
    int w, q, i, l, col;
    if (idx < 8192) {
        w = idx >> 10;
        const int r = idx & 1023;
        const int t2 = r >> 6;
        q = t2 >> 1; i = t2 & 1; l = r & 63;
        col = 8 * l + i;
    } else {
        const int j = idx - 8192;
        w = j / 3072;
        const int r = j - 3072 * w;
        const int t2 = r >> 6;
        q = t2 / 6; i = t2 - 6 * q; l = r & 63;
        col = 8 * l + 2 + i;
    }
    const int kb = 64 * w + 8 * q;
    uint4 o;
    o.x = ldpair(Whh, kb + 0, col);
    o.y = ldpair(Whh, kb + 2, col);
    o.z = ldpair(Whh, kb + 4, col);
    o.w = ldpair(Whh, kb + 6, col);
    Wpk[idx] = o;
}

// ---------------- Phase 1: U[m][n] = u[m][:] @ W_uh[:,n] + b_h[n]  (f16 out) ----------------
__global__ __launch_bounds__(256) void u_gemm(
        const float* __restrict__ A,    // u  [M][NI]
        const float* __restrict__ Bw,   // W_uh [NI][NH]
        const float* __restrict__ bh,   // [NH]
        u16* __restrict__ C) {          // U [M][NH] f16
    const int n0 = blockIdx.x * 64;
    const int m0 = blockIdx.y * 64;
    const int tid = threadIdx.x;
    const int tn = tid & 15, tm = tid >> 4;
    __shared__ float As[64][68];   // [k][m]
    __shared__ float Bs[64][68];   // [k][n]
    float acc[4][4] = {};
    for (int k0 = 0; k0 < NI; k0 += 64) {
        const int r = tid >> 4, c4 = tid & 15;
        #pragma unroll
        for (int p = 0; p < 4; ++p) {
            const int row = r + p * 16;
            float4 v = *reinterpret_cast<const float4*>(&A[(size_t)(m0 + row) * NI + k0 + c4 * 4]);
            As[c4 * 4 + 0][row] = v.x; As[c4 * 4 + 1][row] = v.y;
            As[c4 * 4 + 2][row] = v.z; As[c4 * 4 + 3][row] = v.w;
        }
        #pragma unroll
        for (int p = 0; p < 4; ++p) {
            const int row = r + p * 16;
            float4 v = *reinterpret_cast<const float4*>(&Bw[(size_t)(k0 + row) * NH + n0 + c4 * 4]);
            *reinterpret_cast<float4*>(&Bs[row][c4 * 4]) = v;
        }
        __syncthreads();
        #pragma unroll
        for (int kk = 0; kk < 64; ++kk) {
            float4 av = *reinterpret_cast<const float4*>(&As[kk][tm * 4]);
            float4 bv = *reinterpret_cast<const float4*>(&Bs[kk][tn * 4]);
            const float am[4] = {av.x, av.y, av.z, av.w};
            const float bn[4] = {bv.x, bv.y, bv.z, bv.w};
            #pragma unroll
            for (int i = 0; i < 4; ++i)
                #pragma unroll
                for (int j = 0; j < 4; ++j)
                    acc[i][j] += am[i] * bn[j];
        }
        __syncthreads();
    }
    float bias[4];
    #pragma unroll
    for (int j = 0; j < 4; ++j) bias[j] = bh[n0 + tn * 4 + j];
    #pragma unroll
    for (int i = 0; i < 4; ++i) {
        const int m = m0 + tm * 4 + i;
        ushort4 out;
        out.x = ftoh(acc[i][0] + bias[0]);
        out.y = ftoh(acc[i][1] + bias[1]);
        out.z = ftoh(acc[i][2] + bias[2]);
        out.w = ftoh(acc[i][3] + bias[3]);
        *reinterpret_cast<ushort4*>(&C[(size_t)m * NH + n0 + tn * 4]) = out;
    }
}

// ---------------- Phase 2: sequential recurrence ----------------
// One quad against one column: 4 v_pk_fma_f16, pairs x,z -> even acc, y,w -> odd acc.
#define DOTQ(HQ, WQ, AE, AO)                       \
    AE = fmah2(BCH((HQ).x), BCH((WQ).x), AE);      \
    AO = fmah2(BCH((HQ).y), BCH((WQ).y), AO);      \
    AE = fmah2(BCH((HQ).z), BCH((WQ).z), AE);      \
    AO = fmah2(BCH((HQ).w), BCH((WQ).w), AO);

#define GDOTS(HQ, D0, D1, P0, P1, P2, P3, P4, P5)  \
    DOTQ(HQ, D0, ae0, ao0) DOTQ(HQ, D1, ae1, ao1)  \
    DOTQ(HQ, P0, ae2, ao2) DOTQ(HQ, P1, ae3, ao3)  \
    DOTQ(HQ, P2, ae4, ao4) DOTQ(HQ, P3, ae5, ao5)  \
    DOTQ(HQ, P4, ae6, ao6) DOTQ(HQ, P5, ae7, ao7)

// Refill one 6-quad stream group; imm offsets small, second ptr covers slots 4,5.
#define REFILL(P0, P1, P2, P3, P4, P5)             \
    P0 = wcurA[0];   P1 = wcurA[64];               \
    P2 = wcurA[128]; P3 = wcurA[192];              \
    P4 = wcurB[0];   P5 = wcurB[64];               \
    wcurA += 384; wcurB += 384;

__global__ __launch_bounds__(512)
void rnn_seq(const float* __restrict__ h0,    // [NB][NH]
             const u16* __restrict__ U,       // [NB*NT][NH] f16
             u16* __restrict__ H,             // [NB*NT][NH] f16 (out)
             const uint4* __restrict__ Wpk) { // packed W_hh f16, 32768 uint4
    const int b = blockIdx.x;
    const int tid = threadIdx.x;
    const int w = tid >> 6, l = tid & 63;

    __shared__ __align__(16) uint4 Wlds[8192];       // LDS-resident W slice, 128 KiB
    __shared__ __align__(16) float part2[8][8][72];  // partials, 18 KiB, conflict-free
    __shared__ __align__(16) u32 h2u[NH / 2];        // h as f16 pairs, 1 KiB

    // One-time copy of section A into LDS (coalesced b128).
    #pragma unroll
    for (int j = 0; j < 16; ++j) Wlds[j * 512 + tid] = Wpk[j * 512 + tid];

    float hreg = h0[b * NH + tid];
    if (tid < NH / 2) {
        float2 hv = *reinterpret_cast<const float2*>(&h0[b * NH + 2 * tid]);
        half2_t hp; hp[0] = (_Float16)hv.x; hp[1] = (_Float16)hv.y;
        h2u[tid] = __builtin_bit_cast(u32, hp);
    }
    __syncthreads();

    const u16* __restrict__ Urow = U + (size_t)b * NT * NH + tid;
    u16* __restrict__ Hrow = H + (size_t)b * NT * NH + tid;
    const uint4* __restrict__ ws0 = Wpk + 8192 + (size_t)w * 3072 + l;  // stream base (g0)
    const uint4* __restrict__ wlw = Wlds + w * 1024 + l;                // LDS-W base
    const uint4* __restrict__ hqb = reinterpret_cast<const uint4*>(h2u) + (w << 3);

    // Stream double-buffer: 12 named quads, primed with groups g0 (pa) and g1 (pb).
    const uint4* wcurA = ws0;
    const uint4* wcurB = ws0 + 256;
    uint4 pa0, pa1, pa2, pa3, pa4, pa5, pb0, pb1, pb2, pb3, pb4, pb5;
    REFILL(pa0, pa1, pa2, pa3, pa4, pa5)   // g0; wcurA -> g1
    REFILL(pb0, pb1, pb2, pb3, pb4, pb5)   // g1; wcurA -> g2 (loop steady state)

    // LDS-W rolling pair, primed with group 0's quads.
    uint4 dA0 = wlw[0], dA1 = wlw[64];
    uint4 dB0, dB1;

    u16 ub_cur = Urow[0];
    const half2_t hz = (half2_t)(_Float16)0.f;

    #pragma unroll 1
    for (int t = 0; t < NT; ++t) {
        const u16 ub_nxt = Urow[(size_t)(t + 1) * NH];   // one step ahead (safe: H follows U)

        uint4 hqA = hqb[0], hqB = hqb[1];
        half2_t ae0 = hz, ae1 = hz, ae2 = hz, ae3 = hz, ae4 = hz, ae5 = hz, ae6 = hz, ae7 = hz;
        half2_t ao0 = hz, ao1 = hz, ao2 = hz, ao3 = hz, ao4 = hz, ao5 = hz, ao6 = hz, ao7 = hz;

        // G0
        dB0 = wlw[2 * 64]; dB1 = wlw[3 * 64];
        GDOTS(hqA, dA0, dA1, pa0, pa1, pa2, pa3, pa4, pa5)
        hqA = hqb[2];
        REFILL(pa0, pa1, pa2, pa3, pa4, pa5)   // g2
        // G1
        dA0 = wlw[4 * 64]; dA1 = wlw[5 * 64];
        GDOTS(hqB, dB0, dB1, pb0, pb1, pb2, pb3, pb4, pb5)
        hqB = hqb[3];
        REFILL(pb0, pb1, pb2, pb3, pb4, pb5)   // g3
        // G2
        dB0 = wlw[6 * 64]; dB1 = wlw[7 * 64];
        GDOTS(hqA, dA0, dA1, pa0, pa1, pa2, pa3, pa4, pa5)
        hqA = hqb[4];
        REFILL(pa0, pa1, pa2, pa3, pa4, pa5)   // g4
        // G3
        dA0 = wlw[8 * 64]; dA1 = wlw[9 * 64];
        GDOTS(hqB, dB0, dB1, pb0, pb1, pb2, pb3, pb4, pb5)
        hqB = hqb[5];
        REFILL(pb0, pb1, pb2, pb3, pb4, pb5)   // g5
        // G4
        dB0 = wlw[10 * 64]; dB1 = wlw[11 * 64];
        GDOTS(hqA, dA0, dA1, pa0, pa1, pa2, pa3, pa4, pa5)
        hqA = hqb[6];
        REFILL(pa0, pa1, pa2, pa3, pa4, pa5)   // g6
        // G5
        dA0 = wlw[12 * 64]; dA1 = wlw[13 * 64];
        GDOTS(hqB, dB0, dB1, pb0, pb1, pb2, pb3, pb4, pb5)
        hqB = hqb[7];
        REFILL(pb0, pb1, pb2, pb3, pb4, pb5)   // g7
        wcurA = ws0; wcurB = ws0 + 256;        // rewind for g0/g1
        // G6
        dB0 = wlw[14 * 64]; dB1 = wlw[15 * 64];
        GDOTS(hqA, dA0, dA1, pa0, pa1, pa2, pa3, pa4, pa5)
        REFILL(pa0, pa1, pa2, pa3, pa4, pa5)   // g0 (next step)
        // G7
        dA0 = wlw[0]; dA1 = wlw[64];           // next step's g0 quads
        GDOTS(hqB, dB0, dB1, pb0, pb1, pb2, pb3, pb4, pb5)
        REFILL(pb0, pb1, pb2, pb3, pb4, pb5)   // g1 (next step); wcurA -> g2

        // Partials: col 8l+i -> part2[w][i][l]; lanes consecutive => conflict-free.
        part2[w][0][l] = hsum4(ae0, ao0); part2[w][1][l] = hsum4(ae1, ao1);
        part2[w][2][l] = hsum4(ae2, ao2); part2[w][3][l] = hsum4(ae3, ao3);
        part2[w][4][l] = hsum4(ae4, ao4); part2[w][5][l] = hsum4(ae5, ao5);
        part2[w][6][l] = hsum4(ae6, ao6); part2[w][7][l] = hsum4(ae7, ao7);
        __syncthreads();

        // Update h[tid]: 8-way k-chunk reduction; 72%32=8 => 8i+l distinct => free.
        const int ii = tid & 7, lr = tid >> 3;
        const float pre = (((part2[0][ii][lr] + part2[1][ii][lr])
                          + (part2[2][ii][lr] + part2[3][ii][lr]))
                         + ((part2[4][ii][lr] + part2[5][ii][lr])
                          + (part2[6][ii][lr] + part2[7][ii][lr])))
                        + htof(ub_cur);
        const float e = __expf(2.f * pre);
        hreg = 0.9f * hreg + 0.1f * (1.f - 2.f / (e + 1.f));
        const u16 hb = ftoh(hreg);
        Hrow[(size_t)t * NH] = hb;
        reinterpret_cast<u16*>(h2u)[tid] = hb;
        ub_cur = ub_nxt;
        __syncthreads();
    }
}

// ---------------- Phase 3: Y[m][n] = H[m][:] @ W_hy[:,n] + b_y[n]  (fp32 out) ----------------
__global__ __launch_bounds__(256) void y_gemm(
        const u16* __restrict__ H,      // [M][NH] f16
        const float* __restrict__ Why,  // [NH][NO]
        const float* __restrict__ by,   // [NO]
        float* __restrict__ Y) {        // [M][NO]
    const int m0 = blockIdx.x * 64;
    const int tid = threadIdx.x;
    const int tn = tid & 15, tm = tid >> 4;
    __shared__ float As[64][68];    // [k][m]
    __shared__ float Bs[64][132];   // [k][n]
    float acc[4][8] = {};
    for (int k0 = 0; k0 < NH; k0 += 64) {
        #pragma unroll
        for (int p = 0; p < 4; ++p) {
            const int idx = tid + p * 256;
            const int r = idx >> 4;
            const int c4 = idx & 15;
            ushort4 v = *reinterpret_cast<const ushort4*>(&H[(size_t)(m0 + r) * NH + k0 + c4 * 4]);
            As[c4 * 4 + 0][r] = htof(v.x); As[c4 * 4 + 1][r] = htof(v.y);
            As[c4 * 4 + 2][r] = htof(v.z); As[c4 * 4 + 3][r] = htof(v.w);
        }
        #pragma unroll
        for (int p = 0; p < 8; ++p) {
            const int idx = tid + p * 256;
            const int r = idx >> 5;
            const int c4 = idx & 31;
            float4 v = *reinterpret_cast<const float4*>(&Why[(size_t)(k0 + r) * NO + c4 * 4]);
            *reinterpret_cast<float4*>(&Bs[r][c4 * 4]) = v;
        }
        __syncthreads();
        #pragma unroll
        for (int kk = 0; kk < 64; ++kk) {
            float4 av = *reinterpret_cast<const float4*>(&As[kk][tm * 4]);
            float4 b0 = *reinterpret_cast<const float4*>(&Bs[kk][tn * 8]);
            float4 b1 = *reinterpret_cast<const float4*>(&Bs[kk][tn * 8 + 4]);
            const float am[4] = {av.x, av.y, av.z, av.w};
            const float bn[8] = {b0.x, b0.y, b0.z, b0.w, b1.x, b1.y, b1.z, b1.w};
            #pragma unroll
            for (int i = 0; i < 4; ++i)
                #pragma unroll
                for (int j = 0; j < 8; ++j)
                    acc[i][j] += am[i] * bn[j];
        }
        __syncthreads();
    }
    float bias[8];
    #pragma unroll
    for (int j = 0; j < 8; ++j) bias[j] = by[tn * 8 + j];
    #pragma unroll
    for (int i = 0; i < 4; ++i) {
        const int m = m0 + tm * 4 + i;
        float4 o0, o1;
        o0.x = acc[i][0] + bias[0]; o0.y = acc[i][1] + bias[1];
        o0.z = acc[i][2] + bias[2]; o0.w = acc[i][3] + bias[3];
        o1.x = acc[i][4] + bias[4]; o1.y = acc[i][5] + bias[5];
        o1.z = acc[i][6] + bias[6]; o1.w = acc[i][7] + bias[7];
        *reinterpret_cast<float4*>(&Y[(size_t)m * NO + tn * 8]) = o0;
        *reinterpret_cast<float4*>(&Y[(size_t)m * NO + tn * 8 + 4]) = o1;
    }
}

extern "C" void kernel_launch(void* const* d_in, const int* in_sizes, int n_in,
                              void* d_out, int out_size, void* d_ws, size_t ws_size,
                              hipStream_t stream) {
    const float* u   = (const float*)d_in[0];   // [64][2048][128]
    const float* h0  = (const float*)d_in[1];   // [64][512]
    const float* Wuh = (const float*)d_in[2];   // [128][512]
    const float* Whh = (const float*)d_in[3];   // [512][512]
    const float* Why = (const float*)d_in[4];   // [512][128]
    const float* bh  = (const float*)d_in[5];   // [512]
    const float* by  = (const float*)d_in[6];   // [128]
    float* y = (float*)d_out;                   // [64][2048][128] fp32

    u16* Uws = (u16*)d_ws;                       // 128 MiB
    u16* Hws = Uws + (size_t)NB * NT * NH;       // 128 MiB
    uint4* Wpk = (uint4*)d_out;                  // 512 KiB, dead until y_gemm
    (void)in_sizes; (void)n_in; (void)out_size; (void)ws_size;

    wpack<<<dim3(128), 256, 0, stream>>>(Whh, Wpk);
    u_gemm<<<dim3(NH / 64, (NB * NT) / 64), 256, 0, stream>>>(u, Wuh, bh, Uws);
    rnn_seq<<<dim3(NB), 512, 0, stream>>>(h0, Uws, Hws, Wpk);
    y_gemm<<<dim3((NB * NT) / 64), 256, 0, stream>>>(Hws, Why, by, y);
}

// Round 8
// 3610.788 us; speedup vs baseline: 1.1664x; 1.1664x over previous
//
#include <hip/hip_runtime.h>
#include <cmath>

// Leaky RNN:  h_t = 0.9 h_{t-1} + 0.1 tanh(h W_hh + u_t W_uh + b_h);  y_t = h_t W_hy + b_y
// B=64, T=2048, N_in=128, N_h=512, N_out=128.
//
// Phase 2 (critical path): one WG per batch row, 512 threads = 8 waves, fits the 128-VGPR
// pin.  W_hh: 2 of 8 cols/lane LDS-resident (128 KiB, step-invariant) + 6 cols streamed
// from L2 (384 KB/step/CU) through a 2-group double buffer of 12 named uint4.
// MACs via v_dot2_f32_f16, 8 f32 accumulators, COLUMN-MAJOR order per h-quad
// (h.x across all 8 cols, then h.y, ...) so accumulator reuse distance = 8 instrs
// (round 6/7 lesson: 4 back-to-back MACs into one acc = latency-bound at ~2x cost).
// Partials in part2[8][8][72] (conflict-free).  h broadcast via LDS f16 pairs;
// U prefetched one step ahead; 2 barriers/step.
//
// ws: U (f16 [B*T][512], 128 MiB) | H (f16 [B*T][512], 128 MiB).
// Wpk (512 KiB packed f16 W_hh) lives in d_out (dead until y_gemm runs last).

#define NB 64
#define NT 2048
#define NI 128
#define NH 512
#define NO 128

typedef unsigned short u16;
typedef unsigned int u32;
typedef _Float16 half2_t __attribute__((ext_vector_type(2)));

__device__ __forceinline__ float fdot2(half2_t a, half2_t b, float c) {
#if __has_builtin(__builtin_amdgcn_fdot2)
    return __builtin_amdgcn_fdot2(a, b, c, false);
#else
    return c + (float)a[0] * (float)b[0] + (float)a[1] * (float)b[1];
#endif
}
#define BCH(u) __builtin_bit_cast(half2_t, (u))

__device__ __forceinline__ u16 ftoh(float x) { return __builtin_bit_cast(u16, (_Float16)x); }
__device__ __forceinline__ float htof(u16 x) { return (float)__builtin_bit_cast(_Float16, x); }

__device__ __forceinline__ u32 ldpair(const float* __restrict__ W, int k, int c) {
    half2_t v;
    v[0] = (_Float16)W[(size_t)k * NH + c];
    v[1] = (_Float16)W[(size_t)(k + 1) * NH + c];
    return __builtin_bit_cast(u32, v);
}

// ---------------- Phase 0: pack W_hh to f16 in consumer order ----------------
// Section A (LDS-resident, idx<8192):  w=idx>>10, r=idx&1023, t2=r>>6, q=t2>>1, i=t2&1,
//   l=r&63, col=8l+i.
// Section B (streamed, idx>=8192): j=idx-8192, w=j/3072, r=j%3072, t2=r>>6, q=t2/6,
//   i=t2%6, l=r&63, col=8l+2+i.
// Quad = k-pairs {kb,kb+2,kb+4,kb+6}, kb=64w+8q.
__global__ __launch_bounds__(256) void wpack(const float* __restrict__ Whh,
                                             uint4* __restrict__ Wpk) {
    const int idx = blockIdx.x * 256 + threadIdx.x;   // 0..32767
    int w, q, i, l, col;
    if (idx < 8192) {
        w = idx >> 10;
        const int r = idx & 1023;
        const int t2 = r >> 6;
        q = t2 >> 1; i = t2 & 1; l = r & 63;
        col = 8 * l + i;
    } else {
        const int j = idx - 8192;
        w = j / 3072;
        const int r = j - 3072 * w;
        const int t2 = r >> 6;
        q = t2 / 6; i = t2 - 6 * q; l = r & 63;
        col = 8 * l + 2 + i;
    }
    const int kb = 64 * w + 8 * q;
    uint4 o;
    o.x = ldpair(Whh, kb + 0, col);
    o.y = ldpair(Whh, kb + 2, col);
    o.z = ldpair(Whh, kb + 4, col);
    o.w = ldpair(Whh, kb + 6, col);
    Wpk[idx] = o;
}

// ---------------- Phase 1: U[m][n] = u[m][:] @ W_uh[:,n] + b_h[n]  (f16 out) ----------------
__global__ __launch_bounds__(256) void u_gemm(
        const float* __restrict__ A,    // u  [M][NI]
        const float* __restrict__ Bw,   // W_uh [NI][NH]
        const float* __restrict__ bh,   // [NH]
        u16* __restrict__ C) {          // U [M][NH] f16
    const int n0 = blockIdx.x * 64;
    const int m0 = blockIdx.y * 64;
    const int tid = threadIdx.x;
    const int tn = tid & 15, tm = tid >> 4;
    __shared__ float As[64][68];   // [k][m]
    __shared__ float Bs[64][68];   // [k][n]
    float acc[4][4] = {};
    for (int k0 = 0; k0 < NI; k0 += 64) {
        const int r = tid >> 4, c4 = tid & 15;
        #pragma unroll
        for (int p = 0; p < 4; ++p) {
            const int row = r + p * 16;
            float4 v = *reinterpret_cast<const float4*>(&A[(size_t)(m0 + row) * NI + k0 + c4 * 4]);
            As[c4 * 4 + 0][row] = v.x; As[c4 * 4 + 1][row] = v.y;
            As[c4 * 4 + 2][row] = v.z; As[c4 * 4 + 3][row] = v.w;
        }
        #pragma unroll
        for (int p = 0; p < 4; ++p) {
            const int row = r + p * 16;
            float4 v = *reinterpret_cast<const float4*>(&Bw[(size_t)(k0 + row) * NH + n0 + c4 * 4]);
            *reinterpret_cast<float4*>(&Bs[row][c4 * 4]) = v;
        }
        __syncthreads();
        #pragma unroll
        for (int kk = 0; kk < 64; ++kk) {
            float4 av = *reinterpret_cast<const float4*>(&As[kk][tm * 4]);
            float4 bv = *reinterpret_cast<const float4*>(&Bs[kk][tn * 4]);
            const float am[4] = {av.x, av.y, av.z, av.w};
            const float bn[4] = {bv.x, bv.y, bv.z, bv.w};
            #pragma unroll
            for (int i = 0; i < 4; ++i)
                #pragma unroll
                for (int j = 0; j < 4; ++j)
                    acc[i][j] += am[i] * bn[j];
        }
        __syncthreads();
    }
    float bias[4];
    #pragma unroll
    for (int j = 0; j < 4; ++j) bias[j] = bh[n0 + tn * 4 + j];
    #pragma unroll
    for (int i = 0; i < 4; ++i) {
        const int m = m0 + tm * 4 + i;
        ushort4 out;
        out.x = ftoh(acc[i][0] + bias[0]);
        out.y = ftoh(acc[i][1] + bias[1]);
        out.z = ftoh(acc[i][2] + bias[2]);
        out.w = ftoh(acc[i][3] + bias[3]);
        *reinterpret_cast<ushort4*>(&C[(size_t)m * NH + n0 + tn * 4]) = out;
    }
}

// ---------------- Phase 2: sequential recurrence ----------------
// One h-element row across all 8 columns: accumulator reuse distance = 8 instructions.
#define GROW(HE, D0, D1, P0, P1, P2, P3, P4, P5, E)    \
    acc0 = fdot2(HE, BCH((D0).E), acc0);               \
    acc1 = fdot2(HE, BCH((D1).E), acc1);               \
    acc2 = fdot2(HE, BCH((P0).E), acc2);               \
    acc3 = fdot2(HE, BCH((P1).E), acc3);               \
    acc4 = fdot2(HE, BCH((P2).E), acc4);               \
    acc5 = fdot2(HE, BCH((P3).E), acc5);               \
    acc6 = fdot2(HE, BCH((P4).E), acc6);               \
    acc7 = fdot2(HE, BCH((P5).E), acc7);

#define GDOTS(HQ, D0, D1, P0, P1, P2, P3, P4, P5) {                     \
    const half2_t hx = BCH((HQ).x), hy = BCH((HQ).y);                   \
    const half2_t hzz = BCH((HQ).z), hww = BCH((HQ).w);                 \
    GROW(hx,  D0, D1, P0, P1, P2, P3, P4, P5, x)                        \
    GROW(hy,  D0, D1, P0, P1, P2, P3, P4, P5, y)                        \
    GROW(hzz, D0, D1, P0, P1, P2, P3, P4, P5, z)                        \
    GROW(hww, D0, D1, P0, P1, P2, P3, P4, P5, w) }

// Refill one 6-quad stream group; imm offsets small, second ptr covers slots 4,5.
#define REFILL(P0, P1, P2, P3, P4, P5)             \
    P0 = wcurA[0];   P1 = wcurA[64];               \
    P2 = wcurA[128]; P3 = wcurA[192];              \
    P4 = wcurB[0];   P5 = wcurB[64];               \
    wcurA += 384; wcurB += 384;

__global__ __launch_bounds__(512)
void rnn_seq(const float* __restrict__ h0,    // [NB][NH]
             const u16* __restrict__ U,       // [NB*NT][NH] f16
             u16* __restrict__ H,             // [NB*NT][NH] f16 (out)
             const uint4* __restrict__ Wpk) { // packed W_hh f16, 32768 uint4
    const int b = blockIdx.x;
    const int tid = threadIdx.x;
    const int w = tid >> 6, l = tid & 63;

    __shared__ __align__(16) uint4 Wlds[8192];       // LDS-resident W slice, 128 KiB
    __shared__ __align__(16) float part2[8][8][72];  // partials, 18 KiB, conflict-free
    __shared__ __align__(16) u32 h2u[NH / 2];        // h as f16 pairs, 1 KiB

    // One-time copy of section A into LDS (coalesced b128).
    #pragma unroll
    for (int j = 0; j < 16; ++j) Wlds[j * 512 + tid] = Wpk[j * 512 + tid];

    float hreg = h0[b * NH + tid];
    if (tid < NH / 2) {
        float2 hv = *reinterpret_cast<const float2*>(&h0[b * NH + 2 * tid]);
        half2_t hp; hp[0] = (_Float16)hv.x; hp[1] = (_Float16)hv.y;
        h2u[tid] = __builtin_bit_cast(u32, hp);
    }
    __syncthreads();

    const u16* __restrict__ Urow = U + (size_t)b * NT * NH + tid;
    u16* __restrict__ Hrow = H + (size_t)b * NT * NH + tid;
    const uint4* __restrict__ ws0 = Wpk + 8192 + (size_t)w * 3072 + l;  // stream base (g0)
    const uint4* __restrict__ wlw = Wlds + w * 1024 + l;                // LDS-W base
    const uint4* __restrict__ hqb = reinterpret_cast<const uint4*>(h2u) + (w << 3);

    // Stream double-buffer: 12 named quads, primed with groups g0 (pa) and g1 (pb).
    const uint4* wcurA = ws0;
    const uint4* wcurB = ws0 + 256;
    uint4 pa0, pa1, pa2, pa3, pa4, pa5, pb0, pb1, pb2, pb3, pb4, pb5;
    REFILL(pa0, pa1, pa2, pa3, pa4, pa5)   // g0; wcurA -> g1
    REFILL(pb0, pb1, pb2, pb3, pb4, pb5)   // g1; wcurA -> g2 (loop steady state)

    // LDS-W rolling pair, primed with group 0's quads.
    uint4 dA0 = wlw[0], dA1 = wlw[64];
    uint4 dB0, dB1;

    u16 ub_cur = Urow[0];

    #pragma unroll 1
    for (int t = 0; t < NT; ++t) {
        const u16 ub_nxt = Urow[(size_t)(t + 1) * NH];   // one step ahead (safe: H follows U)

        uint4 hqA = hqb[0], hqB = hqb[1];
        float acc0 = 0.f, acc1 = 0.f, acc2 = 0.f, acc3 = 0.f;
        float acc4 = 0.f, acc5 = 0.f, acc6 = 0.f, acc7 = 0.f;

        // G0
        dB0 = wlw[2 * 64]; dB1 = wlw[3 * 64];
        GDOTS(hqA, dA0, dA1, pa0, pa1, pa2, pa3, pa4, pa5)
        hqA = hqb[2];
        REFILL(pa0, pa1, pa2, pa3, pa4, pa5)   // g2
        // G1
        dA0 = wlw[4 * 64]; dA1 = wlw[5 * 64];
        GDOTS(hqB, dB0, dB1, pb0, pb1, pb2, pb3, pb4, pb5)
        hqB = hqb[3];
        REFILL(pb0, pb1, pb2, pb3, pb4, pb5)   // g3
        // G2
        dB0 = wlw[6 * 64]; dB1 = wlw[7 * 64];
        GDOTS(hqA, dA0, dA1, pa0, pa1, pa2, pa3, pa4, pa5)
        hqA = hqb[4];
        REFILL(pa0, pa1, pa2, pa3, pa4, pa5)   // g4
        // G3
        dA0 = wlw[8 * 64]; dA1 = wlw[9 * 64];
        GDOTS(hqB, dB0, dB1, pb0, pb1, pb2, pb3, pb4, pb5)
        hqB = hqb[5];
        REFILL(pb0, pb1, pb2, pb3, pb4, pb5)   // g5
        // G4
        dB0 = wlw[10 * 64]; dB1 = wlw[11 * 64];
        GDOTS(hqA, dA0, dA1, pa0, pa1, pa2, pa3, pa4, pa5)
        hqA = hqb[6];
        REFILL(pa0, pa1, pa2, pa3, pa4, pa5)   // g6
        // G5
        dA0 = wlw[12 * 64]; dA1 = wlw[13 * 64];
        GDOTS(hqB, dB0, dB1, pb0, pb1, pb2, pb3, pb4, pb5)
        hqB = hqb[7];
        REFILL(pb0, pb1, pb2, pb3, pb4, pb5)   // g7
        wcurA = ws0; wcurB = ws0 + 256;        // rewind for g0/g1
        // G6
        dB0 = wlw[14 * 64]; dB1 = wlw[15 * 64];
        GDOTS(hqA, dA0, dA1, pa0, pa1, pa2, pa3, pa4, pa5)
        REFILL(pa0, pa1, pa2, pa3, pa4, pa5)   // g0 (next step)
        // G7
        dA0 = wlw[0]; dA1 = wlw[64];           // next step's g0 quads
        GDOTS(hqB, dB0, dB1, pb0, pb1, pb2, pb3, pb4, pb5)
        REFILL(pb0, pb1, pb2, pb3, pb4, pb5)   // g1 (next step); wcurA -> g2

        // Partials: col 8l+i -> part2[w][i][l]; lanes consecutive => conflict-free.
        part2[w][0][l] = acc0; part2[w][1][l] = acc1;
        part2[w][2][l] = acc2; part2[w][3][l] = acc3;
        part2[w][4][l] = acc4; part2[w][5][l] = acc5;
        part2[w][6][l] = acc6; part2[w][7][l] = acc7;
        __syncthreads();

        // Update h[tid]: 8-way k-chunk reduction; 72%32=8 => 8i+l distinct => free.
        const int ii = tid & 7, lr = tid >> 3;
        const float pre = (((part2[0][ii][lr] + part2[1][ii][lr])
                          + (part2[2][ii][lr] + part2[3][ii][lr]))
                         + ((part2[4][ii][lr] + part2[5][ii][lr])
                          + (part2[6][ii][lr] + part2[7][ii][lr])))
                        + htof(ub_cur);
        const float e = __expf(2.f * pre);
        hreg = 0.9f * hreg + 0.1f * (1.f - 2.f / (e + 1.f));
        const u16 hb = ftoh(hreg);
        Hrow[(size_t)t * NH] = hb;
        reinterpret_cast<u16*>(h2u)[tid] = hb;
        ub_cur = ub_nxt;
        __syncthreads();
    }
}

// ---------------- Phase 3: Y[m][n] = H[m][:] @ W_hy[:,n] + b_y[n]  (fp32 out) ----------------
__global__ __launch_bounds__(256) void y_gemm(
        const u16* __restrict__ H,      // [M][NH] f16
        const float* __restrict__ Why,  // [NH][NO]
        const float* __restrict__ by,   // [NO]
        float* __restrict__ Y) {        // [M][NO]
    const int m0 = blockIdx.x * 64;
    const int tid = threadIdx.x;
    const int tn = tid & 15, tm = tid >> 4;
    __shared__ float As[64][68];    // [k][m]
    __shared__ float Bs[64][132];   // [k][n]
    float acc[4][8] = {};
    for (int k0 = 0; k0 < NH; k0 += 64) {
        #pragma unroll
        for (int p = 0; p < 4; ++p) {
            const int idx = tid + p * 256;
            const int r = idx >> 4;
            const int c4 = idx & 15;
            ushort4 v = *reinterpret_cast<const ushort4*>(&H[(size_t)(m0 + r) * NH + k0 + c4 * 4]);
            As[c4 * 4 + 0][r] = htof(v.x); As[c4 * 4 + 1][r] = htof(v.y);
            As[c4 * 4 + 2][r] = htof(v.z); As[c4 * 4 + 3][r] = htof(v.w);
        }
        #pragma unroll
        for (int p = 0; p < 8; ++p) {
            const int idx = tid + p * 256;
            const int r = idx >> 5;
            const int c4 = idx & 31;
            float4 v = *reinterpret_cast<const float4*>(&Why[(size_t)(k0 + r) * NO + c4 * 4]);
            *reinterpret_cast<float4*>(&Bs[r][c4 * 4]) = v;
        }
        __syncthreads();
        #pragma unroll
        for (int kk = 0; kk < 64; ++kk) {
            float4 av = *reinterpret_cast<const float4*>(&As[kk][tm * 4]);
            float4 b0 = *reinterpret_cast<const float4*>(&Bs[kk][tn * 8]);
            float4 b1 = *reinterpret_cast<const float4*>(&Bs[kk][tn * 8 + 4]);
            const float am[4] = {av.x, av.y, av.z, av.w};
            const float bn[8] = {b0.x, b0.y, b0.z, b0.w, b1.x, b1.y, b1.z, b1.w};
            #pragma unroll
            for (int i = 0; i < 4; ++i)
                #pragma unroll
                for (int j = 0; j < 8; ++j)
                    acc[i][j] += am[i] * bn[j];
        }
        __syncthreads();
    }
    float bias[8];
    #pragma unroll
    for (int j = 0; j < 8; ++j) bias[j] = by[tn * 8 + j];
    #pragma unroll
    for (int i = 0; i < 4; ++i) {
        const int m = m0 + tm * 4 + i;
        float4 o0, o1;
        o0.x = acc[i][0] + bias[0]; o0.y = acc[i][1] + bias[1];
        o0.z = acc[i][2] + bias[2]; o0.w = acc[i][3] + bias[3];
        o1.x = acc[i][4] + bias[4]; o1.y = acc[i][5] + bias[5];
        o1.z = acc[i][6] + bias[6]; o1.w = acc[i][7] + bias[7];
        *reinterpret_cast<float4*>(&Y[(size_t)m * NO + tn * 8]) = o0;
        *reinterpret_cast<float4*>(&Y[(size_t)m * NO + tn * 8 + 4]) = o1;
    }
}

extern "C" void kernel_launch(void* const* d_in, const int* in_sizes, int n_in,
                              void* d_out, int out_size, void* d_ws, size_t ws_size,
                              hipStream_t stream) {
    const float* u   = (const float*)d_in[0];   // [64][2048][128]
    const float* h0  = (const float*)d_in[1];   // [64][512]
    const float* Wuh = (const float*)d_in[2];   // [128][512]
    const float* Whh = (const float*)d_in[3];   // [512][512]
    const float* Why = (const float*)d_in[4];   // [512][128]
    const float* bh  = (const float*)d_in[5];   // [512]
    const float* by  = (const float*)d_in[6];   // [128]
    float* y = (float*)d_out;                   // [64][2048][128] fp32

    u16* Uws = (u16*)d_ws;                       // 128 MiB
    u16* Hws = Uws + (size_t)NB * NT * NH;       // 128 MiB
    uint4* Wpk = (uint4*)d_out;                  // 512 KiB, dead until y_gemm
    (void)in_sizes; (void)n_in; (void)out_size; (void)ws_size;

    wpack<<<dim3(128), 256, 0, stream>>>(Whh, Wpk);
    u_gemm<<<dim3(NH / 64, (NB * NT) / 64), 256, 0, stream>>>(u, Wuh, bh, Uws);
    rnn_seq<<<dim3(NB), 512, 0, stream>>>(h0, Uws, Hws, Wpk);
    y_gemm<<<dim3((NB * NT) / 64), 256, 0, stream>>>(Hws, Why, by, y);
}